// Round 10
// baseline (253.440 us; speedup 1.0000x reference)
//
#include <hip/hip_runtime.h>
#include <math.h>

#define NMAT   16384
#define CHEB_A 0.08
#define CHEB_B 7.0
#define DDEG   29            // Chebyshev degree (odd); truncation tail ~5e-4 on [a,b]
#define NCOEF  (DDEG + 1)
#define NITER  ((DDEG - 1) / 2)   // Clenshaw pair-iterations
#define NLOGBLK 1024         // k_logsum blocks
#define NWAVES4 (NLOGBLK * 4) // 4096 waves; each wave owns 4 matrices (stride NWAVES4)
#define NOUTBLK 1024         // k_out blocks
#define NOUTWV  (NOUTBLK * 4)

// ws float layout
#define WS_GQ    0
#define WS_GSQ   1024
#define WS_C     2112
#define WS_CT    3136

// d_out float scratch layout (consumed before final kernel overwrites):
#define OUT_PA   0          // 256*1024  (stage-1 partial sums of X)
#define OUT_PL   262144     // 1024*1024 (stage-3 partial sums of log)
#define OUT_PL2  1310720    // 32*1024

typedef __attribute__((ext_vector_type(8)))  short short8;   // 8 bf16 (4 VGPRs)
typedef __attribute__((ext_vector_type(16))) float f32x16;   // MFMA 32x32 C/D
typedef __attribute__((ext_vector_type(2)))  float f32x2;
typedef __attribute__((ext_vector_type(2)))  __bf16 bf16x2;

union FB { short8 v; unsigned int w[4]; };

// row of C/D-layout register r for half h: (r&3) + 8*(r>>2) + 4*h
#define ROWOF(r, h) (((r) & 3) + 8 * ((r) >> 2) + 4 * (h))

// round-half-up f32->bf16, pack pair into one dword (lo=a, hi=b). Split-path
// (keeps hi/lo splits exactly consistent with rhi()).
__device__ __forceinline__ unsigned int pk2(float a, float b) {
    unsigned int au = __float_as_uint(a) + 0x8000u;
    unsigned int bu = __float_as_uint(b) + 0x8000u;
    return __builtin_amdgcn_perm(bu, au, 0x07060302u);
}
__device__ __forceinline__ float rhi(float x) {   // bf16-rounded value as float
    return __uint_as_float((__float_as_uint(x) + 0x8000u) & 0xffff0000u);
}

// hot-path pack: RNE pack of 2 f32 -> 2 bf16 (lo=a, hi=b), compiler-emitted
// (vector fptrunc; gfx950 backend selects v_cvt_pk_bf16_f32 itself).
__device__ __forceinline__ unsigned int cvt2(float a, float b) {
    f32x2 s; s.x = a; s.y = b;
    bf16x2 t = __builtin_convertvector(s, bf16x2);
    unsigned int r;
    __builtin_memcpy(&r, &t, 4);
    return r;
}

// D (C/D layout fp32) -> two B-operand k-half fragments, pure in-register.
// NEG bakes a sign flip into the conversion (free input modifier) — used by the
// sign-alternated Clenshaw so the MFMA C-input is always a pure accumulate.
template <bool HALF, bool NEG>
__device__ __forceinline__ void toB(const f32x16& d, FB& b1, FB& b2) {
    unsigned int p[8];
#pragma unroll
    for (int g = 0; g < 8; ++g) {
        float s0 = d[2 * g], s1 = d[2 * g + 1];
        if (HALF) { s0 *= 0.5f; s1 *= 0.5f; }
        if (NEG)  { s0 = -s0; s1 = -s1; }
        p[g] = cvt2(s0, s1);
    }
    auto r02 = __builtin_amdgcn_permlane32_swap(p[0], p[2], false, false);
    auto r13 = __builtin_amdgcn_permlane32_swap(p[1], p[3], false, false);
    auto r46 = __builtin_amdgcn_permlane32_swap(p[4], p[6], false, false);
    auto r57 = __builtin_amdgcn_permlane32_swap(p[5], p[7], false, false);
    b1.w[0] = r02[0]; b1.w[1] = r13[0]; b1.w[2] = r02[1]; b1.w[3] = r13[1];
    b2.w[0] = r46[0]; b2.w[1] = r57[0]; b2.w[2] = r46[1]; b2.w[3] = r57[1];
}

#define MFMA(a, b, c) __builtin_amdgcn_mfma_f32_32x32x16_bf16((a), (b), (c), 0, 0, 0)

// ---- hi/lo split fragments of a symmetric matrix in C/D layout.
struct SplitM { FB h1, h2, l1, l2; };

__device__ __forceinline__ void splitB(const f32x16& d, SplitM& s) {
    unsigned int ph[8], pl[8];
#pragma unroll
    for (int g = 0; g < 8; ++g) {
        float a = d[2 * g], b = d[2 * g + 1];
        ph[g] = pk2(a, b);
        pl[g] = pk2(a - rhi(a), b - rhi(b));
    }
    auto h02 = __builtin_amdgcn_permlane32_swap(ph[0], ph[2], false, false);
    auto h13 = __builtin_amdgcn_permlane32_swap(ph[1], ph[3], false, false);
    auto h46 = __builtin_amdgcn_permlane32_swap(ph[4], ph[6], false, false);
    auto h57 = __builtin_amdgcn_permlane32_swap(ph[5], ph[7], false, false);
    s.h1.w[0] = h02[0]; s.h1.w[1] = h13[0]; s.h1.w[2] = h02[1]; s.h1.w[3] = h13[1];
    s.h2.w[0] = h46[0]; s.h2.w[1] = h57[0]; s.h2.w[2] = h46[1]; s.h2.w[3] = h57[1];
    auto l02 = __builtin_amdgcn_permlane32_swap(pl[0], pl[2], false, false);
    auto l13 = __builtin_amdgcn_permlane32_swap(pl[1], pl[3], false, false);
    auto l46 = __builtin_amdgcn_permlane32_swap(pl[4], pl[6], false, false);
    auto l57 = __builtin_amdgcn_permlane32_swap(pl[5], pl[7], false, false);
    s.l1.w[0] = l02[0]; s.l1.w[1] = l13[0]; s.l1.w[2] = l02[1]; s.l1.w[3] = l13[1];
    s.l2.w[0] = l46[0]; s.l2.w[1] = l57[0]; s.l2.w[2] = l46[1]; s.l2.w[3] = l57[1];
}

// D = A*B for split operands. The fragment duality: a B-frag set of matrix M,
// fed as the A-operand, represents M^T. So A here must be either a symmetric
// matrix's frags, or the frags of (desired A)^T.
__device__ __forceinline__ f32x16 mulSS(const SplitM& A, const SplitM& B) {
    f32x16 d;
#pragma unroll
    for (int r = 0; r < 16; ++r) d[r] = 0.f;
    d = MFMA(A.h2.v, B.l2.v, d); d = MFMA(A.h1.v, B.l1.v, d);
    d = MFMA(A.l2.v, B.h2.v, d); d = MFMA(A.l1.v, B.h1.v, d);
    d = MFMA(A.h2.v, B.h2.v, d); d = MFMA(A.h1.v, B.h1.v, d);
    return d;
}

// build split frags directly from a row-major 32x32 global/ws tile, reading
// M[col][k] per lane (the Gq load pattern) -> B-frags of M without permlane.
__device__ __forceinline__ void loadSplit(const float* __restrict__ base,
                                          int col, int h, SplitM& s) {
    const float* p = base + col * 32 + 8 * h;
    float4 a = *(const float4*)(p);
    float4 b = *(const float4*)(p + 4);
    float4 c = *(const float4*)(p + 16);
    float4 d = *(const float4*)(p + 20);
    s.h1.w[0] = pk2(a.x, a.y); s.h1.w[1] = pk2(a.z, a.w);
    s.h1.w[2] = pk2(b.x, b.y); s.h1.w[3] = pk2(b.z, b.w);
    s.h2.w[0] = pk2(c.x, c.y); s.h2.w[1] = pk2(c.z, c.w);
    s.h2.w[2] = pk2(d.x, d.y); s.h2.w[3] = pk2(d.z, d.w);
    s.l1.w[0] = pk2(a.x - rhi(a.x), a.y - rhi(a.y));
    s.l1.w[1] = pk2(a.z - rhi(a.z), a.w - rhi(a.w));
    s.l1.w[2] = pk2(b.x - rhi(b.x), b.y - rhi(b.y));
    s.l1.w[3] = pk2(b.z - rhi(b.z), b.w - rhi(b.w));
    s.l2.w[0] = pk2(c.x - rhi(c.x), c.y - rhi(c.y));
    s.l2.w[1] = pk2(c.z - rhi(c.z), c.w - rhi(c.w));
    s.l2.w[2] = pk2(d.x - rhi(d.x), d.y - rhi(d.y));
    s.l2.w[3] = pk2(d.z - rhi(d.z), d.w - rhi(d.w));
}

__device__ __forceinline__ float wred(float v) {   // 64-lane sum, broadcast
    v += __shfl_xor(v, 32);
    v += __shfl_xor(v, 16);
    v += __shfl_xor(v, 8);
    v += __shfl_xor(v, 4);
    v += __shfl_xor(v, 2);
    v += __shfl_xor(v, 1);
    return v;
}

// ---------------- block-level 32x32 matmul on LDS (row-major), 256 threads ----------------
__device__ __forceinline__ void mm32(const float* A, const float* B, float* D, int t) {
    int i = t >> 3, j0 = (t & 7) * 4;
    float a[32];
#pragma unroll
    for (int q = 0; q < 8; ++q) {
        float4 v = *(const float4*)&A[i * 32 + q * 4];
        a[4 * q] = v.x; a[4 * q + 1] = v.y; a[4 * q + 2] = v.z; a[4 * q + 3] = v.w;
    }
    float ax = 0.f, ay = 0.f, az = 0.f, aw = 0.f;
#pragma unroll
    for (int k = 0; k < 32; ++k) {
        float4 bv = *(const float4*)&B[k * 32 + j0];
        ax += a[k] * bv.x; ay += a[k] * bv.y; az += a[k] * bv.z; aw += a[k] * bv.w;
    }
    float4 r = { ax, ay, az, aw };
    *(float4*)&D[i * 32 + j0] = r;
}

// ---------------- K1: partial sums (256 blocks x 64 matrices) ----------------
__global__ __launch_bounds__(256) void k_psum(const float4* __restrict__ X4,
                                              float4* __restrict__ pA4) {
    int b = blockIdx.x, t = threadIdx.x;
    float4 acc = { 0.f, 0.f, 0.f, 0.f };
    for (int r = 0; r < 64; ++r) {
        float4 v = X4[(size_t)(b * 64 + r) * 256 + t];
        acc.x += v.x; acc.y += v.y; acc.z += v.z; acc.w += v.w;
    }
    pA4[b * 256 + t] = acc;
}

// ---------------- K2: finalize G, G^{1/2}, G^{-1/2} ----------------
__global__ __launch_bounds__(256) void k_setup(const float4* __restrict__ pA4,
                                               float* __restrict__ ws) {
    __shared__ alignas(16) float sG[1024], sE[1024], sPa[1024], sPb[1024], sS1[1024], sS2[1024];
    __shared__ float sc[2];
    int t = threadIdx.x;
    float4 acc = { 0.f, 0.f, 0.f, 0.f };
    for (int b = 0; b < 256; ++b) {
        float4 v = pA4[b * 256 + t];
        acc.x += v.x; acc.y += v.y; acc.z += v.z; acc.w += v.w;
    }
    const float invM = 1.0f / (float)NMAT;
    sG[4 * t + 0] = acc.x * invM; sG[4 * t + 1] = acc.y * invM;
    sG[4 * t + 2] = acc.z * invM; sG[4 * t + 3] = acc.w * invM;
    __syncthreads();
    if (t == 0) { float s = 0.f; for (int d = 0; d < 32; ++d) s += sG[d * 33]; sc[0] = s / 32.0f; }
    __syncthreads();
    float c = sc[0];
    int i = t >> 3, j0 = (t & 7) * 4;
#pragma unroll
    for (int q = 0; q < 4; ++q) {
        int e = i * 32 + j0 + q;
        sE[e] = sG[e] / c - ((i == j0 + q) ? 1.f : 0.f);
    }
    __syncthreads();
    const float alp[9] = { 1.f, 0.5f, -0.125f, 0.0625f, -0.0390625f, 0.02734375f,
                           -0.0205078125f, 0.01611328125f, -0.013092041015625f };
    const float bet[9] = { 1.f, -0.5f, 0.375f, -0.3125f, 0.2734375f, -0.24609375f,
                           0.2255859375f, -0.20947265625f, 0.196380615234375f };
#pragma unroll
    for (int q = 0; q < 4; ++q) {
        int e = i * 32 + j0 + q;
        float d = (i == j0 + q) ? 1.f : 0.f;
        sS1[e] = d + alp[1] * sE[e];
        sS2[e] = d + bet[1] * sE[e];
        sPa[e] = sE[e];
    }
    __syncthreads();
    {
        float* P = sPa; float* Pn = sPb;
        for (int k = 2; k <= 8; ++k) {
            mm32(P, sE, Pn, t);
            __syncthreads();
#pragma unroll
            for (int q = 0; q < 4; ++q) {
                int e = i * 32 + j0 + q;
                sS1[e] += alp[k] * Pn[e];
                sS2[e] += bet[k] * Pn[e];
            }
            float* tmp = P; P = Pn; Pn = tmp;
            __syncthreads();
        }
    }
    float rc = sqrtf(c);
#pragma unroll
    for (int q = 0; q < 4; ++q) {
        int e = i * 32 + j0 + q;
        ws[WS_GSQ + e] = rc * sS1[e];
        ws[WS_GQ + e]  = sS2[e] / rc;
    }
}

// ---------------- K3: sum of matrix logs, quad-chain MFMA Clenshaw ----------------
// Sign-alternated Clenshaw: stored iterate y_s = sigma_s * b_(28-s) with sigma
// pattern (+,+,-,-) period 4 => recurrence y_new = (sigma*c)I + y_old + M*(+-y_cur).
// The C-input is a pure accumulate (no VALU prep); the +- on the M-product is
// baked into toB<NEG> (free cvt modifier: X0 frags plain, X1 frags NEG); the
// (sigma*c)I add runs on the MFMA pipe via sparse identity-operand MFMAs with
// the coefficient split bf16 hi+lo (rel err ~2^-17). tm/tsh fold into
// sqrt(tm)-scaled Gq frags + an MFMA-built tsh*I seed: zero VALU T-prep, dm gone.
__global__ __launch_bounds__(256, 2) void k_logsum(const float* __restrict__ Xg,
                                                   const float* __restrict__ ws,
                                                   float* __restrict__ pL) {
    __shared__ float sLacc[1024];
    __shared__ float scheb[NCOEF];
    int t = threadIdx.x;
    for (int e = t; e < 1024; e += 256) sLacc[e] = 0.f;
    if (t < NCOEF) {
        // closed-form Chebyshev coeffs of log on [a,b]
        float alpha = 0.5f * (float)(CHEB_A + CHEB_B);
        float beta  = 0.5f * (float)(CHEB_B - CHEB_A);
        float dd = beta / alpha, s = sqrtf(1.f - dd * dd), tt = dd / (1.f + s);
        float v;
        if (t == 0) v = 2.f * (logf(alpha) + logf(0.5f * (1.f + s)));
        else        v = 2.f * ((t & 1) ? 1.f : -1.f) * exp2f((float)t * log2f(tt)) / (float)t;
        scheb[t] = v;
    }
    const int wv = t >> 6, lane = t & 63, h = lane >> 5, col = lane & 31;

    // identity-element masks in B-frag layout: lane's I element (k==col) sits in
    // frag1 iff col>>3==h (k-slots 8h..8h+7), frag2 iff col>>3==h+2; slot=col&7,
    // dword=slot>>1, half=slot&1 (lo=even slot per cvt2 packing).
    const int inf1 = ((col >> 3) == h);
    const int inf2 = ((col >> 3) == h + 2);
    const int slot = col & 7;
    const unsigned int hm = (slot & 1) ? 0xFFFF0000u : 0x0000FFFFu;
    unsigned int mI1[4], mI2[4];
#pragma unroll
    for (int j = 0; j < 4; ++j) {
        mI1[j] = (inf1 && (slot >> 1) == j) ? hm : 0u;
        mI2[j] = (inf2 && (slot >> 1) == j) ? hm : 0u;
    }
    FB IA1, IA2;   // bf16 identity fragments (A-operand; I symmetric)
#pragma unroll
    for (int j = 0; j < 4; ++j) {
        IA1.w[j] = mI1[j] & 0x3F803F80u;
        IA2.w[j] = mI2[j] & 0x3F803F80u;
    }

    const float m2v = 2.0f / (float)(CHEB_B - CHEB_A);
    const float shv = (float)((CHEB_A + CHEB_B) / (CHEB_B - CHEB_A));
    const float tm = 2.f * m2v, tsh = -2.f * shv;
    const float stm = sqrtf(tm);

    // sqrt(tm)-scaled Gq fragments, hi/lo split (symmetric: A- and B-operand)
    FB GqH1, GqH2, GqL1, GqL2;
    {
        const float* Gqp = ws + WS_GQ + col * 32 + 8 * h;
        float4 ga = *(const float4*)(Gqp);
        float4 gb = *(const float4*)(Gqp + 4);
        float4 gc = *(const float4*)(Gqp + 16);
        float4 gd = *(const float4*)(Gqp + 20);
        ga.x *= stm; ga.y *= stm; ga.z *= stm; ga.w *= stm;
        gb.x *= stm; gb.y *= stm; gb.z *= stm; gb.w *= stm;
        gc.x *= stm; gc.y *= stm; gc.z *= stm; gc.w *= stm;
        gd.x *= stm; gd.y *= stm; gd.z *= stm; gd.w *= stm;
        GqH1.w[0] = pk2(ga.x, ga.y); GqH1.w[1] = pk2(ga.z, ga.w);
        GqH1.w[2] = pk2(gb.x, gb.y); GqH1.w[3] = pk2(gb.z, gb.w);
        GqH2.w[0] = pk2(gc.x, gc.y); GqH2.w[1] = pk2(gc.z, gc.w);
        GqH2.w[2] = pk2(gd.x, gd.y); GqH2.w[3] = pk2(gd.z, gd.w);
        GqL1.w[0] = pk2(ga.x - rhi(ga.x), ga.y - rhi(ga.y));
        GqL1.w[1] = pk2(ga.z - rhi(ga.z), ga.w - rhi(ga.w));
        GqL1.w[2] = pk2(gb.x - rhi(gb.x), gb.y - rhi(gb.y));
        GqL1.w[3] = pk2(gb.z - rhi(gb.z), gb.w - rhi(gb.w));
        GqL2.w[0] = pk2(gc.x - rhi(gc.x), gc.y - rhi(gc.y));
        GqL2.w[1] = pk2(gc.z - rhi(gc.z), gc.w - rhi(gc.w));
        GqL2.w[2] = pk2(gd.x - rhi(gd.x), gd.y - rhi(gd.y));
        GqL2.w[3] = pk2(gd.z - rhi(gd.z), gd.w - rhi(gd.w));
    }
    __syncthreads();   // scheb + sLacc ready

    const float cDv = scheb[DDEG], c0h = 0.5f * scheb[0];

    // v*I add on the MFMA pipe: frags of v*I (hi+lo), 4 sparse MFMAs.
#define BUILD_KI(kf, v)                                                      \
    {                                                                        \
        float _v = (v);                                                      \
        unsigned int _uh = cvt2(_v, _v);                                     \
        float _vh = __uint_as_float(_uh & 0xFFFF0000u);                      \
        float _vl = _v - _vh;                                                \
        unsigned int _ul = cvt2(_vl, _vl);                                   \
        _Pragma("unroll")                                                    \
        for (int j = 0; j < 4; ++j) {                                        \
            kf.h1.w[j] = mI1[j] & _uh; kf.h2.w[j] = mI2[j] & _uh;            \
            kf.l1.w[j] = mI1[j] & _ul; kf.l2.w[j] = mI2[j] & _ul;            \
        }                                                                    \
    }
#define ADD_KI(kf, acc)                                                      \
    acc = MFMA(IA1.v, kf.h1.v, acc); acc = MFMA(IA2.v, kf.h2.v, acc);        \
    acc = MFMA(IA1.v, kf.l1.v, acc); acc = MFMA(IA2.v, kf.l2.v, acc);

    const int m0 = blockIdx.x * 4 + wv;

    // ---- load + pack all four matrices
    const float* Xma = Xg + (size_t)(m0)                * 1024 + col * 32 + 8 * h;
    const float* Xmb = Xg + (size_t)(m0 + NWAVES4)      * 1024 + col * 32 + 8 * h;
    const float* Xmc = Xg + (size_t)(m0 + 2 * NWAVES4)  * 1024 + col * 32 + 8 * h;
    const float* Xmd = Xg + (size_t)(m0 + 3 * NWAVES4)  * 1024 + col * 32 + 8 * h;
    FB AXa1, AXa2, AXb1, AXb2, AXc1, AXc2, AXd1, AXd2;
    {
        float4 v0 = *(const float4*)(Xma);
        float4 v1 = *(const float4*)(Xma + 4);
        float4 v2 = *(const float4*)(Xma + 16);
        float4 v3 = *(const float4*)(Xma + 20);
        AXa1.w[0] = cvt2(v0.x, v0.y); AXa1.w[1] = cvt2(v0.z, v0.w);
        AXa1.w[2] = cvt2(v1.x, v1.y); AXa1.w[3] = cvt2(v1.z, v1.w);
        AXa2.w[0] = cvt2(v2.x, v2.y); AXa2.w[1] = cvt2(v2.z, v2.w);
        AXa2.w[2] = cvt2(v3.x, v3.y); AXa2.w[3] = cvt2(v3.z, v3.w);
    }
    {
        float4 v0 = *(const float4*)(Xmb);
        float4 v1 = *(const float4*)(Xmb + 4);
        float4 v2 = *(const float4*)(Xmb + 16);
        float4 v3 = *(const float4*)(Xmb + 20);
        AXb1.w[0] = cvt2(v0.x, v0.y); AXb1.w[1] = cvt2(v0.z, v0.w);
        AXb1.w[2] = cvt2(v1.x, v1.y); AXb1.w[3] = cvt2(v1.z, v1.w);
        AXb2.w[0] = cvt2(v2.x, v2.y); AXb2.w[1] = cvt2(v2.z, v2.w);
        AXb2.w[2] = cvt2(v3.x, v3.y); AXb2.w[3] = cvt2(v3.z, v3.w);
    }
    {
        float4 v0 = *(const float4*)(Xmc);
        float4 v1 = *(const float4*)(Xmc + 4);
        float4 v2 = *(const float4*)(Xmc + 16);
        float4 v3 = *(const float4*)(Xmc + 20);
        AXc1.w[0] = cvt2(v0.x, v0.y); AXc1.w[1] = cvt2(v0.z, v0.w);
        AXc1.w[2] = cvt2(v1.x, v1.y); AXc1.w[3] = cvt2(v1.z, v1.w);
        AXc2.w[0] = cvt2(v2.x, v2.y); AXc2.w[1] = cvt2(v2.z, v2.w);
        AXc2.w[2] = cvt2(v3.x, v3.y); AXc2.w[3] = cvt2(v3.z, v3.w);
    }
    {
        float4 v0 = *(const float4*)(Xmd);
        float4 v1 = *(const float4*)(Xmd + 4);
        float4 v2 = *(const float4*)(Xmd + 16);
        float4 v3 = *(const float4*)(Xmd + 20);
        AXd1.w[0] = cvt2(v0.x, v0.y); AXd1.w[1] = cvt2(v0.z, v0.w);
        AXd1.w[2] = cvt2(v1.x, v1.y); AXd1.w[3] = cvt2(v1.z, v1.w);
        AXd2.w[0] = cvt2(v2.x, v2.y); AXd2.w[1] = cvt2(v2.z, v2.w);
        AXd2.w[2] = cvt2(v3.x, v3.y); AXd2.w[3] = cvt2(v3.z, v3.w);
    }

    // ---- U' = X * Gq' (all chains); Gq' = sqrt(tm)*Gq
    f32x16 Ua, Ub, Uc, Ud;
#pragma unroll
    for (int r = 0; r < 16; ++r) { Ua[r] = 0.f; Ub[r] = 0.f; Uc[r] = 0.f; Ud[r] = 0.f; }
    Ua = MFMA(AXa2.v, GqL2.v, Ua); Ub = MFMA(AXb2.v, GqL2.v, Ub);
    Uc = MFMA(AXc2.v, GqL2.v, Uc); Ud = MFMA(AXd2.v, GqL2.v, Ud);
    Ua = MFMA(AXa1.v, GqL1.v, Ua); Ub = MFMA(AXb1.v, GqL1.v, Ub);
    Uc = MFMA(AXc1.v, GqL1.v, Uc); Ud = MFMA(AXd1.v, GqL1.v, Ud);
    Ua = MFMA(AXa2.v, GqH2.v, Ua); Ub = MFMA(AXb2.v, GqH2.v, Ub);
    Uc = MFMA(AXc2.v, GqH2.v, Uc); Ud = MFMA(AXd2.v, GqH2.v, Ud);
    Ua = MFMA(AXa1.v, GqH1.v, Ua); Ub = MFMA(AXb1.v, GqH1.v, Ub);
    Uc = MFMA(AXc1.v, GqH1.v, Uc); Ud = MFMA(AXd1.v, GqH1.v, Ud);
    FB Ba1, Ba2, Bb1, Bb2, Bc1, Bc2, Bd1, Bd2;
    toB<false, false>(Ua, Ba1, Ba2); toB<false, false>(Ub, Bb1, Bb2);
    toB<false, false>(Uc, Bc1, Bc2); toB<false, false>(Ud, Bd1, Bd2);

    // ---- T = Gq'*U' + tsh*I directly (seed = tsh*I via sparse MFMAs, shared)
    f32x16 Tseed;
#pragma unroll
    for (int r = 0; r < 16; ++r) Tseed[r] = 0.f;
    {
        SplitM kft; BUILD_KI(kft, tsh);
        ADD_KI(kft, Tseed);
    }
    f32x16 Sa = Tseed, Sb = Tseed, Sc = Tseed, Sd = Tseed;
    Sa = MFMA(GqL2.v, Ba2.v, Sa); Sb = MFMA(GqL2.v, Bb2.v, Sb);
    Sc = MFMA(GqL2.v, Bc2.v, Sc); Sd = MFMA(GqL2.v, Bd2.v, Sd);
    Sa = MFMA(GqL1.v, Ba1.v, Sa); Sb = MFMA(GqL1.v, Bb1.v, Sb);
    Sc = MFMA(GqL1.v, Bc1.v, Sc); Sd = MFMA(GqL1.v, Bd1.v, Sd);
    Sa = MFMA(GqH2.v, Ba2.v, Sa); Sb = MFMA(GqH2.v, Bb2.v, Sb);
    Sc = MFMA(GqH2.v, Bc2.v, Sc); Sd = MFMA(GqH2.v, Bd2.v, Sd);
    Sa = MFMA(GqH1.v, Ba1.v, Sa); Sb = MFMA(GqH1.v, Bb1.v, Sb);
    Sc = MFMA(GqH1.v, Bc1.v, Sc); Sd = MFMA(GqH1.v, Bd1.v, Sd);
    FB Aa1, Aa2, Ab1, Ab2, Ac1, Ac2, Ad1, Ad2;
    toB<false, false>(Sa, Aa1, Aa2); toB<false, false>(Sb, Ab1, Ab2);
    toB<false, false>(Sc, Ac1, Ac2); toB<false, false>(Sd, Ad1, Ad2);

    // ---- sign-alternated Clenshaw
    // seeds: y_{-2}=0 (X0), y_{-1}=-c_D*I (X1, built via MFMA); seed frags = +c_D*I
    f32x16 X0a, X1a, X0b, X1b, X0c, X1c, X0d, X1d;
    {
        f32x16 X1s;
#pragma unroll
        for (int r = 0; r < 16; ++r) X1s[r] = 0.f;
        SplitM kfs; BUILD_KI(kfs, -cDv);
        ADD_KI(kfs, X1s);
        X1a = X1s; X1b = X1s; X1c = X1s; X1d = X1s;
#pragma unroll
        for (int r = 0; r < 16; ++r) { X0a[r] = 0.f; X0b[r] = 0.f; X0c[r] = 0.f; X0d[r] = 0.f; }
    }
    {
        unsigned int ucd = cvt2(cDv, cDv);
#pragma unroll
        for (int j = 0; j < 4; ++j) {
            Ba1.w[j] = mI1[j] & ucd; Ba2.w[j] = mI2[j] & ucd;
        }
        Bb1 = Ba1; Bb2 = Ba2; Bc1 = Ba1; Bc2 = Ba2; Bd1 = Ba1; Bd2 = Ba2;
    }
    for (int it = 0; it < NITER; ++it) {
        float sgn = (it & 1) ? -1.f : 1.f;
        float ka = sgn * scheb[DDEG - 1 - 2 * it];
        float kb = sgn * scheb[DDEG - 2 - 2 * it];
        {
            SplitM kfa; BUILD_KI(kfa, ka);
            ADD_KI(kfa, X0a); ADD_KI(kfa, X0b); ADD_KI(kfa, X0c); ADD_KI(kfa, X0d);
        }
        X0a = MFMA(Aa2.v, Ba2.v, X0a); X0b = MFMA(Ab2.v, Bb2.v, X0b);
        X0c = MFMA(Ac2.v, Bc2.v, X0c); X0d = MFMA(Ad2.v, Bd2.v, X0d);
        X0a = MFMA(Aa1.v, Ba1.v, X0a); X0b = MFMA(Ab1.v, Bb1.v, X0b);
        X0c = MFMA(Ac1.v, Bc1.v, X0c); X0d = MFMA(Ad1.v, Bd1.v, X0d);
        toB<false, false>(X0a, Ba1, Ba2); toB<false, false>(X0b, Bb1, Bb2);
        toB<false, false>(X0c, Bc1, Bc2); toB<false, false>(X0d, Bd1, Bd2);
        {
            SplitM kfb; BUILD_KI(kfb, kb);
            ADD_KI(kfb, X1a); ADD_KI(kfb, X1b); ADD_KI(kfb, X1c); ADD_KI(kfb, X1d);
        }
        X1a = MFMA(Aa2.v, Ba2.v, X1a); X1b = MFMA(Ab2.v, Bb2.v, X1b);
        X1c = MFMA(Ac2.v, Bc2.v, X1c); X1d = MFMA(Ad2.v, Bd2.v, X1d);
        X1a = MFMA(Aa1.v, Ba1.v, X1a); X1b = MFMA(Ab1.v, Bb1.v, X1b);
        X1c = MFMA(Ac1.v, Bc1.v, X1c); X1d = MFMA(Ad1.v, Bd1.v, X1d);
        if (it < NITER - 1) {
            toB<false, true>(X1a, Ba1, Ba2); toB<false, true>(X1b, Bb1, Bb2);
            toB<false, true>(X1c, Bc1, Bc2); toB<false, true>(X1d, Bd1, Bd2);
        } else {
            toB<true, true>(X1a, Ba1, Ba2); toB<true, true>(X1b, Bb1, Bb2);   // +0.5*b_1
            toB<true, true>(X1c, Bc1, Bc2); toB<true, true>(X1d, Bd1, Bd2);
        }
    }
    // ---- f = 0.5*c0 I + y_26 + M*(0.5 b_1)   (y_26 = -b_2)
    {
        SplitM kf0; BUILD_KI(kf0, c0h);
        ADD_KI(kf0, X0a); ADD_KI(kf0, X0b); ADD_KI(kf0, X0c); ADD_KI(kf0, X0d);
    }
    X0a = MFMA(Aa2.v, Ba2.v, X0a); X0b = MFMA(Ab2.v, Bb2.v, X0b);
    X0c = MFMA(Ac2.v, Bc2.v, X0c); X0d = MFMA(Ad2.v, Bd2.v, X0d);
    X0a = MFMA(Aa1.v, Ba1.v, X0a); X0b = MFMA(Ab1.v, Bb1.v, X0b);
    X0c = MFMA(Ac1.v, Bc1.v, X0c); X0d = MFMA(Ad1.v, Bd1.v, X0d);

    f32x16 Facc;
#pragma unroll
    for (int r = 0; r < 16; ++r) Facc[r] = (X0a[r] + X0b[r]) + (X0c[r] + X0d[r]);

#pragma unroll
    for (int r = 0; r < 16; ++r) {
        int row = (r & 3) + 8 * (r >> 2) + 4 * h;
        atomicAdd(&sLacc[row * 32 + col], Facc[r]);
    }
    __syncthreads();
    float4 v = *(float4*)&sLacc[4 * t];
    ((float4*)pL)[(size_t)blockIdx.x * 256 + t] = v;
#undef BUILD_KI
#undef ADD_KI
}

// ---------------- K3b: reduce 1024 partials -> 32 ----------------
__global__ __launch_bounds__(256) void k_red32(const float4* __restrict__ pL4,
                                               float4* __restrict__ pL24) {
    int b = blockIdx.x, t = threadIdx.x;
    float4 acc = { 0.f, 0.f, 0.f, 0.f };
    for (int r = 0; r < 32; ++r) {
        float4 v = pL4[(size_t)(b * 32 + r) * 256 + t];
        acc.x += v.x; acc.y += v.y; acc.z += v.z; acc.w += v.w;
    }
    pL24[b * 256 + t] = acc;
}

// ---------------- K4: single-wave MFMA chain: L -> expL -> Gn -> Gn^{-1/2};
//                  W^{1/2}; C = Wsq*Gn_isq. ----------------
__global__ __launch_bounds__(256) void k_final(const float4* __restrict__ pL24,
                                               const float* __restrict__ Wg,
                                               float* __restrict__ ws) {
    __shared__ alignas(16) float sL[1024];
    int t = threadIdx.x;
    // stage: all 256 threads reduce the 32 partials
    {
        float4 acc = { 0.f, 0.f, 0.f, 0.f };
        for (int b = 0; b < 32; ++b) {
            float4 v = pL24[b * 256 + t];
            acc.x += v.x; acc.y += v.y; acc.z += v.z; acc.w += v.w;
        }
        const float invM = 1.0f / (float)NMAT;
        sL[4 * t + 0] = acc.x * invM; sL[4 * t + 1] = acc.y * invM;
        sL[4 * t + 2] = acc.z * invM; sL[4 * t + 3] = acc.w * invM;
    }
    __syncthreads();
    if (t >= 64) return;          // wave 0 only from here (no more barriers)

    const int h = t >> 5, col = t & 31;
    const int hasd = (((col >> 2) & 1) == h);
    const int dreg = 4 * (col >> 3) + (col & 3);
    f32x16 dm;
#pragma unroll
    for (int r = 0; r < 16; ++r) dm[r] = (hasd && r == dreg) ? 1.f : 0.f;

    // mean-L into C/D registers
    f32x16 Lm;
#pragma unroll
    for (int r = 0; r < 16; ++r) Lm[r] = sL[ROWOF(r, h) * 32 + col];

    // s0 = tr(L)/32
    float tr = 0.f;
#pragma unroll
    for (int r = 0; r < 16; ++r) tr = fmaf(Lm[r], dm[r], tr);
    float s0 = wred(tr) / 32.0f;

    f32x16 L0;
#pragma unroll
    for (int r = 0; r < 16; ++r) L0[r] = fmaf(-s0, dm[r], Lm[r]);

    // expm series: E4 = sum_{k=0}^{12} L0^k/k!
    SplitM SL0; splitB(L0, SL0);
    f32x16 E4;
#pragma unroll
    for (int r = 0; r < 16; ++r) E4[r] = dm[r] + L0[r];
    SplitM SP = SL0;
    for (int k = 2; k <= 12; ++k) {
        f32x16 Pn = mulSS(SP, SL0);        // P * L0 (A=P symmetric)
        float invk = 1.0f / (float)k;
#pragma unroll
        for (int r = 0; r < 16; ++r) { Pn[r] *= invk; E4[r] += Pn[r]; }
        if (k < 12) splitB(Pn, SP);
    }
    float es = expf(s0);
#pragma unroll
    for (int r = 0; r < 16; ++r) E4[r] *= es;   // expL

    // Gn = Gsq * (expL * Gsq)
    f32x16 Gs;
#pragma unroll
    for (int r = 0; r < 16; ++r) Gs[r] = ws[WS_GSQ + ROWOF(r, h) * 32 + col];
    SplitM SG; splitB(Gs, SG);
    SplitM SE; splitB(E4, SE);
    f32x16 Mx = mulSS(SE, SG);              // expL*Gsq (A=expL sym; Mx NOT sym)
    SplitM SM; splitB(Mx, SM);
    f32x16 Gn = mulSS(SG, SM);              // A=Gsq sym, B=Mx

    // c2 = tr(Gn)/32; coupled NS x8 for (Gn/c2)^{-1/2}
    float tr2 = 0.f;
#pragma unroll
    for (int r = 0; r < 16; ++r) tr2 = fmaf(Gn[r], dm[r], tr2);
    float c2 = wred(tr2) / 32.0f;
    float ic2 = 1.0f / c2;

    f32x16 YC, ZC;
#pragma unroll
    for (int r = 0; r < 16; ++r) { YC[r] = Gn[r] * ic2; ZC[r] = dm[r]; }
    SplitM SY, SZ, ST;
    splitB(YC, SY); splitB(ZC, SZ);
    for (int it = 0; it < 8; ++it) {
        f32x16 ZY = mulSS(SZ, SY);          // Z*Y (Z sym)
        f32x16 T;
#pragma unroll
        for (int r = 0; r < 16; ++r) T[r] = fmaf(1.5f, dm[r], -0.5f * ZY[r]);
        splitB(T, ST);
        f32x16 Yn = mulSS(SY, ST);          // Y*T (Y sym)
        f32x16 Zn = mulSS(ST, SZ);          // T*Z (T sym)
        YC = Yn; ZC = Zn;
        splitB(YC, SY); splitB(ZC, SZ);
    }
    float rc2 = rsqrtf(c2);
    f32x16 Gi;
#pragma unroll
    for (int r = 0; r < 16; ++r) Gi[r] = ZC[r] * rc2;   // Gn^{-1/2}
    SplitM SGi; splitB(Gi, SGi);

    // W^{1/2}: c3 = ||W||_F; NS x15
    f32x16 Wm;
#pragma unroll
    for (int r = 0; r < 16; ++r) Wm[r] = Wg[ROWOF(r, h) * 32 + col];
    float ss = 0.f;
#pragma unroll
    for (int r = 0; r < 16; ++r) ss = fmaf(Wm[r], Wm[r], ss);
    float c3 = sqrtf(wred(ss));
    float ic3 = 1.0f / c3;
#pragma unroll
    for (int r = 0; r < 16; ++r) { YC[r] = Wm[r] * ic3; ZC[r] = dm[r]; }
    splitB(YC, SY); splitB(ZC, SZ);
    for (int it = 0; it < 15; ++it) {
        f32x16 ZY = mulSS(SZ, SY);
        f32x16 T;
#pragma unroll
        for (int r = 0; r < 16; ++r) T[r] = fmaf(1.5f, dm[r], -0.5f * ZY[r]);
        splitB(T, ST);
        f32x16 Yn = mulSS(SY, ST);
        f32x16 Zn = mulSS(ST, SZ);
        YC = Yn; ZC = Zn;
        splitB(YC, SY); splitB(ZC, SZ);
    }
    float rc3 = sqrtf(c3);
    f32x16 Ws;
#pragma unroll
    for (int r = 0; r < 16; ++r) Ws[r] = YC[r] * rc3;   // W^{1/2}
    SplitM SW; splitB(Ws, SW);

    f32x16 C = mulSS(SW, SGi);              // C = Wsq * Gn_isq (Wsq sym)
#pragma unroll
    for (int r = 0; r < 16; ++r) {
        int row = ROWOF(r, h);
        ws[WS_C + row * 32 + col] = C[r];
        ws[WS_CT + col * 32 + row] = C[r];
    }
}

// ---------------- K5: out = C * X * C^T via MFMA ----------------
// Fragment duality: B-frags of C^T (direct-loaded from WS_C: C^T[k][col] =
// C[col][k] = ws[WS_C + col*32 + k]) serve as (a) the B-operand for V = X*C^T
// and (b) the A-operand for out = C*V. X and V hi/lo-split (3-term products).
__global__ __launch_bounds__(256) void k_out(const float* __restrict__ Xg,
                                             const float* __restrict__ ws,
                                             float* __restrict__ Og) {
    int t = threadIdx.x;
    const int wv = t >> 6, lane = t & 63, h = lane >> 5, col = lane & 31;
    SplitM SCt;
    loadSplit(ws + WS_C, col, h, SCt);   // frags of C^T (constant per wave)

    for (int m = blockIdx.x * 4 + wv; m < NMAT; m += NOUTWV) {
        SplitM SX;
        loadSplit(Xg + (size_t)m * 1024, col, h, SX);   // frags of X (sym)
        f32x16 V = mulSS(SX, SCt);        // V = X * C^T  (A = X, symmetric)
        SplitM SV; splitB(V, SV);
        f32x16 O = mulSS(SCt, SV);        // out = C * V  (A-frags of C = SCt)
        float* Om = Og + (size_t)m * 1024;
#pragma unroll
        for (int r = 0; r < 16; ++r) {
            Om[ROWOF(r, h) * 32 + col] = O[r];
        }
    }
}

extern "C" void kernel_launch(void* const* d_in, const int* in_sizes, int n_in,
                              void* d_out, int out_size, void* d_ws, size_t ws_size,
                              hipStream_t stream) {
    const float* X = (const float*)d_in[0];
    const float* W = (const float*)d_in[1];
    float* out = (float*)d_out;
    float* ws  = (float*)d_ws;
    float* pA  = out + OUT_PA;
    float* pL  = out + OUT_PL;
    float* pL2 = out + OUT_PL2;

    hipLaunchKernelGGL(k_psum,   dim3(256),     dim3(256), 0, stream, (const float4*)X, (float4*)pA);
    hipLaunchKernelGGL(k_setup,  dim3(1),       dim3(256), 0, stream, (const float4*)pA, ws);
    hipLaunchKernelGGL(k_logsum, dim3(NLOGBLK), dim3(256), 0, stream, X, ws, pL);
    hipLaunchKernelGGL(k_red32,  dim3(32),      dim3(256), 0, stream, (const float4*)pL, (float4*)pL2);
    hipLaunchKernelGGL(k_final,  dim3(1),       dim3(256), 0, stream, (const float4*)pL2, W, ws);
    hipLaunchKernelGGL(k_out,    dim3(NOUTBLK), dim3(256), 0, stream, X, ws, out);
}

// Round 11
// 241.639 us; speedup vs baseline: 1.0488x; 1.0488x over previous
//
#include <hip/hip_runtime.h>
#include <math.h>

#define NMAT   16384
#define CHEB_A 0.08
#define CHEB_B 7.0
#define DDEG   29            // Chebyshev degree (odd); truncation tail ~5e-4 on [a,b]
#define NCOEF  (DDEG + 1)
#define NITER  ((DDEG - 1) / 2)   // Clenshaw pair-iterations
#define NLOGBLK 1024         // k_logsum blocks
#define NWAVES4 (NLOGBLK * 4) // 4096 waves; each wave owns 4 matrices (stride NWAVES4)
#define NOUTBLK 1024         // k_out blocks
#define NOUTWV  (NOUTBLK * 4)

// ws float layout
#define WS_GQ    0
#define WS_GSQ   1024
#define WS_C     2112
#define WS_CT    3136

// d_out float scratch layout (consumed before final kernel overwrites):
#define OUT_PA   0          // 256*1024  (stage-1 partial sums of X)
#define OUT_PL   262144     // 1024*1024 (stage-3 partial sums of log)
#define OUT_PL2  1310720    // 32*1024

typedef __attribute__((ext_vector_type(8)))  short short8;   // 8 bf16 (4 VGPRs)
typedef __attribute__((ext_vector_type(16))) float f32x16;   // MFMA 32x32 C/D
typedef __attribute__((ext_vector_type(2)))  float f32x2;
typedef __attribute__((ext_vector_type(2)))  __bf16 bf16x2;

union FB { short8 v; unsigned int w[4]; };

// row of C/D-layout register r for half h: (r&3) + 8*(r>>2) + 4*h
#define ROWOF(r, h) (((r) & 3) + 8 * ((r) >> 2) + 4 * (h))

// round-half-up f32->bf16, pack pair into one dword (lo=a, hi=b). Split-path
// (keeps hi/lo splits exactly consistent with rhi()).
__device__ __forceinline__ unsigned int pk2(float a, float b) {
    unsigned int au = __float_as_uint(a) + 0x8000u;
    unsigned int bu = __float_as_uint(b) + 0x8000u;
    return __builtin_amdgcn_perm(bu, au, 0x07060302u);
}
__device__ __forceinline__ float rhi(float x) {   // bf16-rounded value as float
    return __uint_as_float((__float_as_uint(x) + 0x8000u) & 0xffff0000u);
}

// hot-path pack: RNE pack of 2 f32 -> 2 bf16 (lo=a, hi=b), compiler-emitted
// (vector fptrunc; gfx950 backend selects v_cvt_pk_bf16_f32 itself).
__device__ __forceinline__ unsigned int cvt2(float a, float b) {
    f32x2 s; s.x = a; s.y = b;
    bf16x2 t = __builtin_convertvector(s, bf16x2);
    unsigned int r;
    __builtin_memcpy(&r, &t, 4);
    return r;
}

// D (C/D layout fp32) -> two B-operand k-half fragments, pure in-register.
// C/D layout is column-owned (lane holds col=lane&31, rows (r&3)+8*(r>>2)+4h);
// B layout is also column-owned (lane holds col, k=8h+e). The only data motion
// needed is a half-wave exchange lane <-> lane^32: v_permlane32_swap_b32.
template <bool HALF>
__device__ __forceinline__ void toB(const f32x16& d, FB& b1, FB& b2) {
    unsigned int p[8];
#pragma unroll
    for (int g = 0; g < 8; ++g) {
        float s0 = HALF ? 0.5f * d[2 * g]     : d[2 * g];
        float s1 = HALF ? 0.5f * d[2 * g + 1] : d[2 * g + 1];
        p[g] = cvt2(s0, s1);
    }
    auto r02 = __builtin_amdgcn_permlane32_swap(p[0], p[2], false, false);
    auto r13 = __builtin_amdgcn_permlane32_swap(p[1], p[3], false, false);
    auto r46 = __builtin_amdgcn_permlane32_swap(p[4], p[6], false, false);
    auto r57 = __builtin_amdgcn_permlane32_swap(p[5], p[7], false, false);
    b1.w[0] = r02[0]; b1.w[1] = r13[0]; b1.w[2] = r02[1]; b1.w[3] = r13[1];
    b2.w[0] = r46[0]; b2.w[1] = r57[0]; b2.w[2] = r46[1]; b2.w[3] = r57[1];
}

#define MFMA(a, b, c) __builtin_amdgcn_mfma_f32_32x32x16_bf16((a), (b), (c), 0, 0, 0)

// ---- hi/lo split fragments of a symmetric matrix in C/D layout.
struct SplitM { FB h1, h2, l1, l2; };

__device__ __forceinline__ void splitB(const f32x16& d, SplitM& s) {
    unsigned int ph[8], pl[8];
#pragma unroll
    for (int g = 0; g < 8; ++g) {
        float a = d[2 * g], b = d[2 * g + 1];
        ph[g] = pk2(a, b);
        pl[g] = pk2(a - rhi(a), b - rhi(b));
    }
    auto h02 = __builtin_amdgcn_permlane32_swap(ph[0], ph[2], false, false);
    auto h13 = __builtin_amdgcn_permlane32_swap(ph[1], ph[3], false, false);
    auto h46 = __builtin_amdgcn_permlane32_swap(ph[4], ph[6], false, false);
    auto h57 = __builtin_amdgcn_permlane32_swap(ph[5], ph[7], false, false);
    s.h1.w[0] = h02[0]; s.h1.w[1] = h13[0]; s.h1.w[2] = h02[1]; s.h1.w[3] = h13[1];
    s.h2.w[0] = h46[0]; s.h2.w[1] = h57[0]; s.h2.w[2] = h46[1]; s.h2.w[3] = h57[1];
    auto l02 = __builtin_amdgcn_permlane32_swap(pl[0], pl[2], false, false);
    auto l13 = __builtin_amdgcn_permlane32_swap(pl[1], pl[3], false, false);
    auto l46 = __builtin_amdgcn_permlane32_swap(pl[4], pl[6], false, false);
    auto l57 = __builtin_amdgcn_permlane32_swap(pl[5], pl[7], false, false);
    s.l1.w[0] = l02[0]; s.l1.w[1] = l13[0]; s.l1.w[2] = l02[1]; s.l1.w[3] = l13[1];
    s.l2.w[0] = l46[0]; s.l2.w[1] = l57[0]; s.l2.w[2] = l46[1]; s.l2.w[3] = l57[1];
}

// D = A*B for split operands. The fragment duality: a B-frag set of matrix M,
// fed as the A-operand, represents M^T. So A here must be either a symmetric
// matrix's frags, or the frags of (desired A)^T.
__device__ __forceinline__ f32x16 mulSS(const SplitM& A, const SplitM& B) {
    f32x16 d;
#pragma unroll
    for (int r = 0; r < 16; ++r) d[r] = 0.f;
    d = MFMA(A.h2.v, B.l2.v, d); d = MFMA(A.h1.v, B.l1.v, d);
    d = MFMA(A.l2.v, B.h2.v, d); d = MFMA(A.l1.v, B.h1.v, d);
    d = MFMA(A.h2.v, B.h2.v, d); d = MFMA(A.h1.v, B.h1.v, d);
    return d;
}

// build split frags directly from a row-major 32x32 global/ws tile, reading
// M[col][k] per lane (the Gq load pattern) -> B-frags of M without permlane.
__device__ __forceinline__ void loadSplit(const float* __restrict__ base,
                                          int col, int h, SplitM& s) {
    const float* p = base + col * 32 + 8 * h;
    float4 a = *(const float4*)(p);
    float4 b = *(const float4*)(p + 4);
    float4 c = *(const float4*)(p + 16);
    float4 d = *(const float4*)(p + 20);
    s.h1.w[0] = pk2(a.x, a.y); s.h1.w[1] = pk2(a.z, a.w);
    s.h1.w[2] = pk2(b.x, b.y); s.h1.w[3] = pk2(b.z, b.w);
    s.h2.w[0] = pk2(c.x, c.y); s.h2.w[1] = pk2(c.z, c.w);
    s.h2.w[2] = pk2(d.x, d.y); s.h2.w[3] = pk2(d.z, d.w);
    s.l1.w[0] = pk2(a.x - rhi(a.x), a.y - rhi(a.y));
    s.l1.w[1] = pk2(a.z - rhi(a.z), a.w - rhi(a.w));
    s.l1.w[2] = pk2(b.x - rhi(b.x), b.y - rhi(b.y));
    s.l1.w[3] = pk2(b.z - rhi(b.z), b.w - rhi(b.w));
    s.l2.w[0] = pk2(c.x - rhi(c.x), c.y - rhi(c.y));
    s.l2.w[1] = pk2(c.z - rhi(c.z), c.w - rhi(c.w));
    s.l2.w[2] = pk2(d.x - rhi(d.x), d.y - rhi(d.y));
    s.l2.w[3] = pk2(d.z - rhi(d.z), d.w - rhi(d.w));
}

__device__ __forceinline__ float wred(float v) {   // 64-lane sum, broadcast
    v += __shfl_xor(v, 32);
    v += __shfl_xor(v, 16);
    v += __shfl_xor(v, 8);
    v += __shfl_xor(v, 4);
    v += __shfl_xor(v, 2);
    v += __shfl_xor(v, 1);
    return v;
}

// ---------------- K1: partial sums (256 blocks x 64 matrices) ----------------
__global__ __launch_bounds__(256) void k_psum(const float4* __restrict__ X4,
                                              float4* __restrict__ pA4) {
    int b = blockIdx.x, t = threadIdx.x;
    float4 acc = { 0.f, 0.f, 0.f, 0.f };
    for (int r = 0; r < 64; ++r) {
        float4 v = X4[(size_t)(b * 64 + r) * 256 + t];
        acc.x += v.x; acc.y += v.y; acc.z += v.z; acc.w += v.w;
    }
    pA4[b * 256 + t] = acc;
}

// ---------------- K2: G, then single-wave MFMA coupled-NS for G^{1/2}, G^{-1/2} ----------------
// 256 threads reduce the 256 partials into LDS; wave 0 then runs the coupled
// Newton-Schulz in C/D-layout registers (split-bf16 MFMA products, no barriers).
// G/c ~= I (Wishart mean) so 8 NS iterations are fully converged — more accurate
// than the old order-8 binomial series.
__global__ __launch_bounds__(256) void k_setup(const float4* __restrict__ pA4,
                                               float* __restrict__ ws) {
    __shared__ alignas(16) float sG[1024];
    int t = threadIdx.x;
    {
        float4 acc = { 0.f, 0.f, 0.f, 0.f };
        for (int b = 0; b < 256; ++b) {
            float4 v = pA4[b * 256 + t];
            acc.x += v.x; acc.y += v.y; acc.z += v.z; acc.w += v.w;
        }
        const float invM = 1.0f / (float)NMAT;
        sG[4 * t + 0] = acc.x * invM; sG[4 * t + 1] = acc.y * invM;
        sG[4 * t + 2] = acc.z * invM; sG[4 * t + 3] = acc.w * invM;
    }
    __syncthreads();
    if (t >= 64) return;          // wave 0 only from here (no more barriers)

    const int h = t >> 5, col = t & 31;
    const int hasd = (((col >> 2) & 1) == h);
    const int dreg = 4 * (col >> 3) + (col & 3);
    f32x16 dm;
#pragma unroll
    for (int r = 0; r < 16; ++r) dm[r] = (hasd && r == dreg) ? 1.f : 0.f;

    f32x16 Gm;
#pragma unroll
    for (int r = 0; r < 16; ++r) Gm[r] = sG[ROWOF(r, h) * 32 + col];

    // c = tr(G)/32
    float tr = 0.f;
#pragma unroll
    for (int r = 0; r < 16; ++r) tr = fmaf(Gm[r], dm[r], tr);
    float c = wred(tr) / 32.0f;
    float ic = 1.0f / c;

    // coupled NS: Y -> (G/c)^{1/2}, Z -> (G/c)^{-1/2}
    f32x16 YC, ZC;
#pragma unroll
    for (int r = 0; r < 16; ++r) { YC[r] = Gm[r] * ic; ZC[r] = dm[r]; }
    SplitM SY, SZ, ST;
    splitB(YC, SY); splitB(ZC, SZ);
    for (int it = 0; it < 8; ++it) {
        f32x16 ZY = mulSS(SZ, SY);          // Z*Y (Z sym)
        f32x16 T;
#pragma unroll
        for (int r = 0; r < 16; ++r) T[r] = fmaf(1.5f, dm[r], -0.5f * ZY[r]);
        splitB(T, ST);
        f32x16 Yn = mulSS(SY, ST);          // Y*T (Y sym)
        f32x16 Zn = mulSS(ST, SZ);          // T*Z (T sym)
        YC = Yn; ZC = Zn;
        splitB(YC, SY); splitB(ZC, SZ);
    }
    float rc = sqrtf(c);
    float irc = 1.0f / rc;
#pragma unroll
    for (int r = 0; r < 16; ++r) {
        int row = ROWOF(r, h);
        ws[WS_GSQ + row * 32 + col] = YC[r] * rc;    // G^{1/2}
        ws[WS_GQ  + row * 32 + col] = ZC[r] * irc;   // G^{-1/2}
    }
}

// ---------------- K3: sum of matrix logs, quad-chain MFMA Clenshaw ----------------
// Each wave owns 4 matrices (stride NWAVES4) and runs all four Clenshaw chains
// concurrently: 4 independent dependency chains fill MFMA/VALU latency.
__global__ __launch_bounds__(256, 2) void k_logsum(const float* __restrict__ Xg,
                                                   const float* __restrict__ ws,
                                                   float* __restrict__ pL) {
    __shared__ float sLacc[1024];
    __shared__ float scheb[NCOEF];
    int t = threadIdx.x;
    for (int e = t; e < 1024; e += 256) sLacc[e] = 0.f;
    if (t < NCOEF) {
        // closed-form Chebyshev coeffs of log on [a,b]
        float alpha = 0.5f * (float)(CHEB_A + CHEB_B);
        float beta  = 0.5f * (float)(CHEB_B - CHEB_A);
        float dd = beta / alpha, s = sqrtf(1.f - dd * dd), tt = dd / (1.f + s);
        float v;
        if (t == 0) v = 2.f * (logf(alpha) + logf(0.5f * (1.f + s)));
        else        v = 2.f * ((t & 1) ? 1.f : -1.f) * exp2f((float)t * log2f(tt)) / (float)t;
        scheb[t] = v;
    }
    const int wv = t >> 6, lane = t & 63, h = lane >> 5, col = lane & 31;

    // diagonal mask in C/D layout: row(reg)=(reg&3)+8*(reg>>2)+4h == col
    int hasd = (((col >> 2) & 1) == h);
    int dreg = 4 * (col >> 3) + (col & 3);
    f32x16 dm;
#pragma unroll
    for (int r = 0; r < 16; ++r) dm[r] = (hasd && r == dreg) ? 1.f : 0.f;

    // Gq fragments (symmetric; same regs serve as A- and B-operand), hi/lo split
    FB GqH1, GqH2, GqL1, GqL2;
    {
        SplitM SGq;
        loadSplit(ws + WS_GQ, col, h, SGq);
        GqH1 = SGq.h1; GqH2 = SGq.h2; GqL1 = SGq.l1; GqL2 = SGq.l2;
    }
    __syncthreads();   // scheb + sLacc ready

    const float m2v = 2.0f / (float)(CHEB_B - CHEB_A);
    const float shv = (float)((CHEB_A + CHEB_B) / (CHEB_B - CHEB_A));
    const float tm = 2.f * m2v, tsh = -2.f * shv;
    const float cDv = scheb[DDEG], c0h = 0.5f * scheb[0];

    const int m0 = blockIdx.x * 4 + wv;

    // ---- load + pack all four matrices
    const float* Xma = Xg + (size_t)(m0)                * 1024 + col * 32 + 8 * h;
    const float* Xmb = Xg + (size_t)(m0 + NWAVES4)      * 1024 + col * 32 + 8 * h;
    const float* Xmc = Xg + (size_t)(m0 + 2 * NWAVES4)  * 1024 + col * 32 + 8 * h;
    const float* Xmd = Xg + (size_t)(m0 + 3 * NWAVES4)  * 1024 + col * 32 + 8 * h;
    FB AXa1, AXa2, AXb1, AXb2, AXc1, AXc2, AXd1, AXd2;
    {
        float4 v0 = *(const float4*)(Xma);
        float4 v1 = *(const float4*)(Xma + 4);
        float4 v2 = *(const float4*)(Xma + 16);
        float4 v3 = *(const float4*)(Xma + 20);
        AXa1.w[0] = cvt2(v0.x, v0.y); AXa1.w[1] = cvt2(v0.z, v0.w);
        AXa1.w[2] = cvt2(v1.x, v1.y); AXa1.w[3] = cvt2(v1.z, v1.w);
        AXa2.w[0] = cvt2(v2.x, v2.y); AXa2.w[1] = cvt2(v2.z, v2.w);
        AXa2.w[2] = cvt2(v3.x, v3.y); AXa2.w[3] = cvt2(v3.z, v3.w);
    }
    {
        float4 v0 = *(const float4*)(Xmb);
        float4 v1 = *(const float4*)(Xmb + 4);
        float4 v2 = *(const float4*)(Xmb + 16);
        float4 v3 = *(const float4*)(Xmb + 20);
        AXb1.w[0] = cvt2(v0.x, v0.y); AXb1.w[1] = cvt2(v0.z, v0.w);
        AXb1.w[2] = cvt2(v1.x, v1.y); AXb1.w[3] = cvt2(v1.z, v1.w);
        AXb2.w[0] = cvt2(v2.x, v2.y); AXb2.w[1] = cvt2(v2.z, v2.w);
        AXb2.w[2] = cvt2(v3.x, v3.y); AXb2.w[3] = cvt2(v3.z, v3.w);
    }
    {
        float4 v0 = *(const float4*)(Xmc);
        float4 v1 = *(const float4*)(Xmc + 4);
        float4 v2 = *(const float4*)(Xmc + 16);
        float4 v3 = *(const float4*)(Xmc + 20);
        AXc1.w[0] = cvt2(v0.x, v0.y); AXc1.w[1] = cvt2(v0.z, v0.w);
        AXc1.w[2] = cvt2(v1.x, v1.y); AXc1.w[3] = cvt2(v1.z, v1.w);
        AXc2.w[0] = cvt2(v2.x, v2.y); AXc2.w[1] = cvt2(v2.z, v2.w);
        AXc2.w[2] = cvt2(v3.x, v3.y); AXc2.w[3] = cvt2(v3.z, v3.w);
    }
    {
        float4 v0 = *(const float4*)(Xmd);
        float4 v1 = *(const float4*)(Xmd + 4);
        float4 v2 = *(const float4*)(Xmd + 16);
        float4 v3 = *(const float4*)(Xmd + 20);
        AXd1.w[0] = cvt2(v0.x, v0.y); AXd1.w[1] = cvt2(v0.z, v0.w);
        AXd1.w[2] = cvt2(v1.x, v1.y); AXd1.w[3] = cvt2(v1.z, v1.w);
        AXd2.w[0] = cvt2(v2.x, v2.y); AXd2.w[1] = cvt2(v2.z, v2.w);
        AXd2.w[2] = cvt2(v3.x, v3.y); AXd2.w[3] = cvt2(v3.z, v3.w);
    }

    // ---- U = X * Gq (all chains)
    f32x16 Ua, Ub, Uc, Ud;
#pragma unroll
    for (int r = 0; r < 16; ++r) { Ua[r] = 0.f; Ub[r] = 0.f; Uc[r] = 0.f; Ud[r] = 0.f; }
    Ua = MFMA(AXa2.v, GqL2.v, Ua); Ub = MFMA(AXb2.v, GqL2.v, Ub);
    Uc = MFMA(AXc2.v, GqL2.v, Uc); Ud = MFMA(AXd2.v, GqL2.v, Ud);
    Ua = MFMA(AXa1.v, GqL1.v, Ua); Ub = MFMA(AXb1.v, GqL1.v, Ub);
    Uc = MFMA(AXc1.v, GqL1.v, Uc); Ud = MFMA(AXd1.v, GqL1.v, Ud);
    Ua = MFMA(AXa2.v, GqH2.v, Ua); Ub = MFMA(AXb2.v, GqH2.v, Ub);
    Uc = MFMA(AXc2.v, GqH2.v, Uc); Ud = MFMA(AXd2.v, GqH2.v, Ud);
    Ua = MFMA(AXa1.v, GqH1.v, Ua); Ub = MFMA(AXb1.v, GqH1.v, Ub);
    Uc = MFMA(AXc1.v, GqH1.v, Uc); Ud = MFMA(AXd1.v, GqH1.v, Ud);
    FB Ba1, Ba2, Bb1, Bb2, Bc1, Bc2, Bd1, Bd2;
    toB<false>(Ua, Ba1, Ba2); toB<false>(Ub, Bb1, Bb2);
    toB<false>(Uc, Bc1, Bc2); toB<false>(Ud, Bd1, Bd2);
    // ---- S = Gq * U
    f32x16 Sa, Sb, Sc, Sd;
#pragma unroll
    for (int r = 0; r < 16; ++r) { Sa[r] = 0.f; Sb[r] = 0.f; Sc[r] = 0.f; Sd[r] = 0.f; }
    Sa = MFMA(GqL2.v, Ba2.v, Sa); Sb = MFMA(GqL2.v, Bb2.v, Sb);
    Sc = MFMA(GqL2.v, Bc2.v, Sc); Sd = MFMA(GqL2.v, Bd2.v, Sd);
    Sa = MFMA(GqL1.v, Ba1.v, Sa); Sb = MFMA(GqL1.v, Bb1.v, Sb);
    Sc = MFMA(GqL1.v, Bc1.v, Sc); Sd = MFMA(GqL1.v, Bd1.v, Sd);
    Sa = MFMA(GqH2.v, Ba2.v, Sa); Sb = MFMA(GqH2.v, Bb2.v, Sb);
    Sc = MFMA(GqH2.v, Bc2.v, Sc); Sd = MFMA(GqH2.v, Bd2.v, Sd);
    Sa = MFMA(GqH1.v, Ba1.v, Sa); Sb = MFMA(GqH1.v, Bb1.v, Sb);
    Sc = MFMA(GqH1.v, Bc1.v, Sc); Sd = MFMA(GqH1.v, Bd1.v, Sd);
    // ---- 2*Shat = tm*S + tsh*I -> A-operand frags (symmetric)
    FB Aa1, Aa2, Ab1, Ab2, Ac1, Ac2, Ad1, Ad2;
    {
        f32x16 Ta, Tb, Tc, Td;
#pragma unroll
        for (int r = 0; r < 16; ++r) {
            Ta[r] = fmaf(tm, Sa[r], tsh * dm[r]);
            Tb[r] = fmaf(tm, Sb[r], tsh * dm[r]);
            Tc[r] = fmaf(tm, Sc[r], tsh * dm[r]);
            Td[r] = fmaf(tm, Sd[r], tsh * dm[r]);
        }
        toB<false>(Ta, Aa1, Aa2); toB<false>(Tb, Ab1, Ab2);
        toB<false>(Tc, Ac1, Ac2); toB<false>(Td, Ad1, Ad2);
    }

    // ---- Clenshaw: b_k = c_k I - b_{k+2} + (2Shat)*b_{k+1}, all chains
    f32x16 X0a, X1a, X0b, X1b, X0c, X1c, X0d, X1d;
#pragma unroll
    for (int r = 0; r < 16; ++r) {
        float cd = cDv * dm[r];
        X1a[r] = cd; X0a[r] = 0.f;
        X1b[r] = cd; X0b[r] = 0.f;
        X1c[r] = cd; X0c[r] = 0.f;
        X1d[r] = cd; X0d[r] = 0.f;
    }
    toB<false>(X1a, Ba1, Ba2);       // seed frags of cD*I (shared)
    Bb1 = Ba1; Bb2 = Ba2; Bc1 = Ba1; Bc2 = Ba2; Bd1 = Ba1; Bd2 = Ba2;
    for (int it = 0; it < NITER; ++it) {
        float ka = scheb[DDEG - 1 - 2 * it];
        float kb = scheb[DDEG - 2 - 2 * it];
#pragma unroll
        for (int r = 0; r < 16; ++r) {
            float kd = ka * dm[r];
            X0a[r] = kd - X0a[r];
            X0b[r] = kd - X0b[r];
            X0c[r] = kd - X0c[r];
            X0d[r] = kd - X0d[r];
        }
        X0a = MFMA(Aa2.v, Ba2.v, X0a); X0b = MFMA(Ab2.v, Bb2.v, X0b);
        X0c = MFMA(Ac2.v, Bc2.v, X0c); X0d = MFMA(Ad2.v, Bd2.v, X0d);
        X0a = MFMA(Aa1.v, Ba1.v, X0a); X0b = MFMA(Ab1.v, Bb1.v, X0b);
        X0c = MFMA(Ac1.v, Bc1.v, X0c); X0d = MFMA(Ad1.v, Bd1.v, X0d);
        toB<false>(X0a, Ba1, Ba2); toB<false>(X0b, Bb1, Bb2);
        toB<false>(X0c, Bc1, Bc2); toB<false>(X0d, Bd1, Bd2);
#pragma unroll
        for (int r = 0; r < 16; ++r) {
            float kd = kb * dm[r];
            X1a[r] = kd - X1a[r];
            X1b[r] = kd - X1b[r];
            X1c[r] = kd - X1c[r];
            X1d[r] = kd - X1d[r];
        }
        X1a = MFMA(Aa2.v, Ba2.v, X1a); X1b = MFMA(Ab2.v, Bb2.v, X1b);
        X1c = MFMA(Ac2.v, Bc2.v, X1c); X1d = MFMA(Ad2.v, Bd2.v, X1d);
        X1a = MFMA(Aa1.v, Ba1.v, X1a); X1b = MFMA(Ab1.v, Bb1.v, X1b);
        X1c = MFMA(Ac1.v, Bc1.v, X1c); X1d = MFMA(Ad1.v, Bd1.v, X1d);
        if (it < NITER - 1) {
            toB<false>(X1a, Ba1, Ba2); toB<false>(X1b, Bb1, Bb2);
            toB<false>(X1c, Bc1, Bc2); toB<false>(X1d, Bd1, Bd2);
        } else {
            toB<true>(X1a, Ba1, Ba2); toB<true>(X1b, Bb1, Bb2);   // 0.5*b_1
            toB<true>(X1c, Bc1, Bc2); toB<true>(X1d, Bd1, Bd2);
        }
    }
    // ---- f = 0.5*c0 I - b_2 + (2Shat)*(0.5 b_1)
#pragma unroll
    for (int r = 0; r < 16; ++r) {
        float kd = c0h * dm[r];
        X0a[r] = kd - X0a[r];
        X0b[r] = kd - X0b[r];
        X0c[r] = kd - X0c[r];
        X0d[r] = kd - X0d[r];
    }
    X0a = MFMA(Aa2.v, Ba2.v, X0a); X0b = MFMA(Ab2.v, Bb2.v, X0b);
    X0c = MFMA(Ac2.v, Bc2.v, X0c); X0d = MFMA(Ad2.v, Bd2.v, X0d);
    X0a = MFMA(Aa1.v, Ba1.v, X0a); X0b = MFMA(Ab1.v, Bb1.v, X0b);
    X0c = MFMA(Ac1.v, Bc1.v, X0c); X0d = MFMA(Ad1.v, Bd1.v, X0d);

    f32x16 Facc;
#pragma unroll
    for (int r = 0; r < 16; ++r) Facc[r] = (X0a[r] + X0b[r]) + (X0c[r] + X0d[r]);

#pragma unroll
    for (int r = 0; r < 16; ++r) {
        int row = (r & 3) + 8 * (r >> 2) + 4 * h;
        atomicAdd(&sLacc[row * 32 + col], Facc[r]);
    }
    __syncthreads();
    float4 v = *(float4*)&sLacc[4 * t];
    ((float4*)pL)[(size_t)blockIdx.x * 256 + t] = v;
}

// ---------------- K3b: reduce 1024 partials -> 32 ----------------
__global__ __launch_bounds__(256) void k_red32(const float4* __restrict__ pL4,
                                               float4* __restrict__ pL24) {
    int b = blockIdx.x, t = threadIdx.x;
    float4 acc = { 0.f, 0.f, 0.f, 0.f };
    for (int r = 0; r < 32; ++r) {
        float4 v = pL4[(size_t)(b * 32 + r) * 256 + t];
        acc.x += v.x; acc.y += v.y; acc.z += v.z; acc.w += v.w;
    }
    pL24[b * 256 + t] = acc;
}

// ---------------- K4: single-wave MFMA chain: L -> expL -> Gn -> Gn^{-1/2};
//                  W^{1/2}; C = Wsq*Gn_isq. ----------------
__global__ __launch_bounds__(256) void k_final(const float4* __restrict__ pL24,
                                               const float* __restrict__ Wg,
                                               float* __restrict__ ws) {
    __shared__ alignas(16) float sL[1024];
    int t = threadIdx.x;
    // stage: all 256 threads reduce the 32 partials
    {
        float4 acc = { 0.f, 0.f, 0.f, 0.f };
        for (int b = 0; b < 32; ++b) {
            float4 v = pL24[b * 256 + t];
            acc.x += v.x; acc.y += v.y; acc.z += v.z; acc.w += v.w;
        }
        const float invM = 1.0f / (float)NMAT;
        sL[4 * t + 0] = acc.x * invM; sL[4 * t + 1] = acc.y * invM;
        sL[4 * t + 2] = acc.z * invM; sL[4 * t + 3] = acc.w * invM;
    }
    __syncthreads();
    if (t >= 64) return;          // wave 0 only from here (no more barriers)

    const int h = t >> 5, col = t & 31;
    const int hasd = (((col >> 2) & 1) == h);
    const int dreg = 4 * (col >> 3) + (col & 3);
    f32x16 dm;
#pragma unroll
    for (int r = 0; r < 16; ++r) dm[r] = (hasd && r == dreg) ? 1.f : 0.f;

    // mean-L into C/D registers
    f32x16 Lm;
#pragma unroll
    for (int r = 0; r < 16; ++r) Lm[r] = sL[ROWOF(r, h) * 32 + col];

    // s0 = tr(L)/32
    float tr = 0.f;
#pragma unroll
    for (int r = 0; r < 16; ++r) tr = fmaf(Lm[r], dm[r], tr);
    float s0 = wred(tr) / 32.0f;

    f32x16 L0;
#pragma unroll
    for (int r = 0; r < 16; ++r) L0[r] = fmaf(-s0, dm[r], Lm[r]);

    // expm series: E4 = sum_{k=0}^{12} L0^k/k!
    SplitM SL0; splitB(L0, SL0);
    f32x16 E4;
#pragma unroll
    for (int r = 0; r < 16; ++r) E4[r] = dm[r] + L0[r];
    SplitM SP = SL0;
    for (int k = 2; k <= 12; ++k) {
        f32x16 Pn = mulSS(SP, SL0);        // P * L0 (A=P symmetric)
        float invk = 1.0f / (float)k;
#pragma unroll
        for (int r = 0; r < 16; ++r) { Pn[r] *= invk; E4[r] += Pn[r]; }
        if (k < 12) splitB(Pn, SP);
    }
    float es = expf(s0);
#pragma unroll
    for (int r = 0; r < 16; ++r) E4[r] *= es;   // expL

    // Gn = Gsq * (expL * Gsq)
    f32x16 Gs;
#pragma unroll
    for (int r = 0; r < 16; ++r) Gs[r] = ws[WS_GSQ + ROWOF(r, h) * 32 + col];
    SplitM SG; splitB(Gs, SG);
    SplitM SE; splitB(E4, SE);
    f32x16 Mx = mulSS(SE, SG);              // expL*Gsq (A=expL sym; Mx NOT sym)
    SplitM SM; splitB(Mx, SM);
    f32x16 Gn = mulSS(SG, SM);              // A=Gsq sym, B=Mx

    // c2 = tr(Gn)/32; coupled NS x8 for (Gn/c2)^{-1/2}
    float tr2 = 0.f;
#pragma unroll
    for (int r = 0; r < 16; ++r) tr2 = fmaf(Gn[r], dm[r], tr2);
    float c2 = wred(tr2) / 32.0f;
    float ic2 = 1.0f / c2;

    f32x16 YC, ZC;
#pragma unroll
    for (int r = 0; r < 16; ++r) { YC[r] = Gn[r] * ic2; ZC[r] = dm[r]; }
    SplitM SY, SZ, ST;
    splitB(YC, SY); splitB(ZC, SZ);
    for (int it = 0; it < 8; ++it) {
        f32x16 ZY = mulSS(SZ, SY);          // Z*Y (Z sym)
        f32x16 T;
#pragma unroll
        for (int r = 0; r < 16; ++r) T[r] = fmaf(1.5f, dm[r], -0.5f * ZY[r]);
        splitB(T, ST);
        f32x16 Yn = mulSS(SY, ST);          // Y*T (Y sym)
        f32x16 Zn = mulSS(ST, SZ);          // T*Z (T sym)
        YC = Yn; ZC = Zn;
        splitB(YC, SY); splitB(ZC, SZ);
    }
    float rc2 = rsqrtf(c2);
    f32x16 Gi;
#pragma unroll
    for (int r = 0; r < 16; ++r) Gi[r] = ZC[r] * rc2;   // Gn^{-1/2}
    SplitM SGi; splitB(Gi, SGi);

    // W^{1/2}: c3 = ||W||_F; NS x15
    f32x16 Wm;
#pragma unroll
    for (int r = 0; r < 16; ++r) Wm[r] = Wg[ROWOF(r, h) * 32 + col];
    float ss = 0.f;
#pragma unroll
    for (int r = 0; r < 16; ++r) ss = fmaf(Wm[r], Wm[r], ss);
    float c3 = sqrtf(wred(ss));
    float ic3 = 1.0f / c3;
#pragma unroll
    for (int r = 0; r < 16; ++r) { YC[r] = Wm[r] * ic3; ZC[r] = dm[r]; }
    splitB(YC, SY); splitB(ZC, SZ);
    for (int it = 0; it < 15; ++it) {
        f32x16 ZY = mulSS(SZ, SY);
        f32x16 T;
#pragma unroll
        for (int r = 0; r < 16; ++r) T[r] = fmaf(1.5f, dm[r], -0.5f * ZY[r]);
        splitB(T, ST);
        f32x16 Yn = mulSS(SY, ST);
        f32x16 Zn = mulSS(ST, SZ);
        YC = Yn; ZC = Zn;
        splitB(YC, SY); splitB(ZC, SZ);
    }
    float rc3 = sqrtf(c3);
    f32x16 Ws;
#pragma unroll
    for (int r = 0; r < 16; ++r) Ws[r] = YC[r] * rc3;   // W^{1/2}
    SplitM SW; splitB(Ws, SW);

    f32x16 C = mulSS(SW, SGi);              // C = Wsq * Gn_isq (Wsq sym)
#pragma unroll
    for (int r = 0; r < 16; ++r) {
        int row = ROWOF(r, h);
        ws[WS_C + row * 32 + col] = C[r];
        ws[WS_CT + col * 32 + row] = C[r];
    }
}

// ---------------- K5: out = C * X * C^T via MFMA ----------------
// Fragment duality: B-frags of C^T (direct-loaded from WS_C: C^T[k][col] =
// C[col][k] = ws[WS_C + col*32 + k]) serve as (a) the B-operand for V = X*C^T
// and (b) the A-operand for out = C*V. X and V hi/lo-split (3-term products).
__global__ __launch_bounds__(256) void k_out(const float* __restrict__ Xg,
                                             const float* __restrict__ ws,
                                             float* __restrict__ Og) {
    int t = threadIdx.x;
    const int wv = t >> 6, lane = t & 63, h = lane >> 5, col = lane & 31;
    SplitM SCt;
    loadSplit(ws + WS_C, col, h, SCt);   // frags of C^T (constant per wave)

    for (int m = blockIdx.x * 4 + wv; m < NMAT; m += NOUTWV) {
        SplitM SX;
        loadSplit(Xg + (size_t)m * 1024, col, h, SX);   // frags of X (sym)
        f32x16 V = mulSS(SX, SCt);        // V = X * C^T  (A = X, symmetric)
        SplitM SV; splitB(V, SV);
        f32x16 O = mulSS(SCt, SV);        // out = C * V  (A-frags of C = SCt)
        float* Om = Og + (size_t)m * 1024;
#pragma unroll
        for (int r = 0; r < 16; ++r) {
            Om[ROWOF(r, h) * 32 + col] = O[r];
        }
    }
}

extern "C" void kernel_launch(void* const* d_in, const int* in_sizes, int n_in,
                              void* d_out, int out_size, void* d_ws, size_t ws_size,
                              hipStream_t stream) {
    const float* X = (const float*)d_in[0];
    const float* W = (const float*)d_in[1];
    float* out = (float*)d_out;
    float* ws  = (float*)d_ws;
    float* pA  = out + OUT_PA;
    float* pL  = out + OUT_PL;
    float* pL2 = out + OUT_PL2;

    hipLaunchKernelGGL(k_psum,   dim3(256),     dim3(256), 0, stream, (const float4*)X, (float4*)pA);
    hipLaunchKernelGGL(k_setup,  dim3(1),       dim3(256), 0, stream, (const float4*)pA, ws);
    hipLaunchKernelGGL(k_logsum, dim3(NLOGBLK), dim3(256), 0, stream, X, ws, pL);
    hipLaunchKernelGGL(k_red32,  dim3(32),      dim3(256), 0, stream, (const float4*)pL, (float4*)pL2);
    hipLaunchKernelGGL(k_final,  dim3(1),       dim3(256), 0, stream, (const float4*)pL2, W, ws);
    hipLaunchKernelGGL(k_out,    dim3(NOUTBLK), dim3(256), 0, stream, X, ws, out);
}